// Round 1
// baseline (1760.762 us; speedup 1.0000x reference)
//
#include <hip/hip_runtime.h>
#include <cstddef>

// Model constants
// B=8, C=2, Hf=257, T=2048, D_IN=514, DM=256, NL=4, N=32
// Activations stored as stacked real/imag planes: (b, 2*DM=512, T) fp32.

__device__ __forceinline__ float gelu_tanh(float x) {
    const float x3 = x * x * x;
    const float v  = 0.7978845608028654f * (x + 0.044715f * x3);
    const float e  = __expf(2.f * v);
    const float th = 1.f - 2.f / (e + 1.f);
    return 0.5f * x * (1.f + th);
}

// ---------------- builders: real representation of complex weights ----------------
// A (2G x 2H) = [[Wr, -Wi],[Wi, Wr]],  Wr/Wi are (G x H) row-major.
__global__ __launch_bounds__(256) void build_stack_k(
    const float* __restrict__ Wr, const float* __restrict__ Wi,
    float* __restrict__ A, int G, int H)
{
    long long i = (long long)blockIdx.x * 256 + threadIdx.x;
    const long long tot = (long long)4 * G * H;
    if (i >= tot) return;
    const int W2 = 2 * H;
    const int row = (int)(i / W2), col = (int)(i % W2);
    const int ri = row >= G;
    const int g  = row - ri * G;
    const int ci = col >= H;
    const int hh = col - ci * H;
    const size_t wi_ = (size_t)g * H + hh;
    const float w = ri ? (ci ? Wr[wi_] :  Wi[wi_])
                       : (ci ? -Wi[wi_] : Wr[wi_]);
    A[i] = w;
}

__global__ __launch_bounds__(256) void build_bias_k(
    const float* __restrict__ br, const float* __restrict__ bi,
    float* __restrict__ bias, int G)
{
    const int i = blockIdx.x * 256 + threadIdx.x;
    if (i < G) bias[i] = br[i];
    else if (i < 2 * G) bias[i] = bi[i - G];
}

// ---------------- real GEMM: out(b, M, T) = A(MxK) * act(b, K, T) + bias ----------------
// MODE 0: B from raw x (interleaved (b,514,T,2) -> stacked K=1028), out plane (b,512,T)
// MODE 1: B from plane buffer (b,512,T), out plane (b,512,T)
// MODE 2: B from plane buffer (b,512,T), out interleaved into d_out (b,514,T,2), M=1028
template<int MODE>
__global__ __launch_bounds__(256) void cgemm_k(
    const float* __restrict__ A, const float* __restrict__ bias,
    const float* __restrict__ Bact, float* __restrict__ out, int M, int K)
{
    __shared__ float As[8][132];   // [k][m], padded
    __shared__ float Bs[8][128];   // [k][t]
    const int tid = threadIdx.x;
    const int m0 = blockIdx.x * 128, t0 = blockIdx.y * 128, b = blockIdx.z;
    const int tn = tid & 15, tm = tid >> 4;          // 16x16 threads, 8x8 micro-tile
    const int am = tid >> 1, ak = (tid & 1) * 4;     // A staging coords
    const int bk = tid >> 5, bt = (tid & 31) * 4;    // B staging coords

    float acc[8][8];
#pragma unroll
    for (int i = 0; i < 8; ++i)
#pragma unroll
        for (int j = 0; j < 8; ++j) acc[i][j] = 0.f;

    const int kiter = (K + 7) >> 3;
    for (int kc = 0; kc < kiter; ++kc) {
        const int k0 = kc * 8;
        // ---- stage A tile (128m x 8k), transposed into LDS ----
        {
            float4 v = make_float4(0.f, 0.f, 0.f, 0.f);
            const int gm = m0 + am, gk = k0 + ak;
            if (gm < M) {
                if (gk + 3 < K) {
                    v = *(const float4*)(A + (size_t)gm * K + gk);
                } else {
                    float t4[4] = {0.f, 0.f, 0.f, 0.f};
                    for (int j = 0; j < 4; ++j)
                        if (gk + j < K) t4[j] = A[(size_t)gm * K + gk + j];
                    v = make_float4(t4[0], t4[1], t4[2], t4[3]);
                }
            }
            As[ak + 0][am] = v.x; As[ak + 1][am] = v.y;
            As[ak + 2][am] = v.z; As[ak + 3][am] = v.w;
        }
        // ---- stage B tile (8k x 128t) ----
        {
            const int gk = k0 + bk;
            if (MODE == 0) {
                float t4[4] = {0.f, 0.f, 0.f, 0.f};
                if (gk < K) {
                    const int comp = gk >= 514;
                    const int d = gk - comp * 514;
                    const float* p = Bact + (((size_t)b * 514 + d) * 2048 + (t0 + bt)) * 2 + comp;
                    t4[0] = p[0]; t4[1] = p[2]; t4[2] = p[4]; t4[3] = p[6];
                }
                Bs[bk][bt + 0] = t4[0]; Bs[bk][bt + 1] = t4[1];
                Bs[bk][bt + 2] = t4[2]; Bs[bk][bt + 3] = t4[3];
            } else {
                float4 v = make_float4(0.f, 0.f, 0.f, 0.f);
                if (gk < K) v = *(const float4*)(Bact + ((size_t)b * 512 + gk) * 2048 + t0 + bt);
                *(float4*)&Bs[bk][bt] = v;
            }
        }
        __syncthreads();
#pragma unroll
        for (int k = 0; k < 8; ++k) {
            float a[8], bb[8];
            *(float4*)&a[0]  = *(const float4*)&As[k][tm * 8];
            *(float4*)&a[4]  = *(const float4*)&As[k][tm * 8 + 4];
            *(float4*)&bb[0] = *(const float4*)&Bs[k][tn * 8];
            *(float4*)&bb[4] = *(const float4*)&Bs[k][tn * 8 + 4];
#pragma unroll
            for (int i = 0; i < 8; ++i)
#pragma unroll
                for (int j = 0; j < 8; ++j) acc[i][j] += a[i] * bb[j];
        }
        __syncthreads();
    }
    // ---- epilogue ----
#pragma unroll
    for (int i = 0; i < 8; ++i) {
        const int gm = m0 + tm * 8 + i;
        if (gm >= M) continue;
        const float bs = bias[gm];
        if (MODE == 2) {
            const int comp = gm >= 514;
            const int g = gm - comp * 514;
            float* p = out + (((size_t)b * 514 + g) * 2048 + (t0 + tn * 8)) * 2 + comp;
#pragma unroll
            for (int j = 0; j < 8; ++j) p[2 * j] = acc[i][j] + bs;
        } else {
            float* p = out + ((size_t)b * 512 + gm) * 2048 + t0 + tn * 8;
            *(float4*)p       = make_float4(acc[i][0] + bs, acc[i][1] + bs, acc[i][2] + bs, acc[i][3] + bs);
            *(float4*)(p + 4) = make_float4(acc[i][4] + bs, acc[i][5] + bs, acc[i][6] + bs, acc[i][7] + bs);
        }
    }
}

// ---------------- S4D diagonal SSM scan + D-skip + gelu ----------------
// One wave (64 threads) per (b,h). Lane c owns timesteps [c*32, c*32+32).
// For each mode n: local scan (zero init) -> wave prefix-scan of chunk-final
// states with multiplier w^32 -> carry-correction pass.
__global__ __launch_bounds__(64) void s4scan_k(
    const float* __restrict__ z, float* __restrict__ y,
    const float* __restrict__ log_dt, const float* __restrict__ log_A_real,
    const float* __restrict__ A_imag, const float* __restrict__ C_r,
    const float* __restrict__ C_i, const float* __restrict__ Dsk, int l)
{
    const int h = blockIdx.x, b = blockIdx.y;
    const int lane = threadIdx.x;
    __shared__ float2 wsh[32], csh[32];
    __shared__ float dsh;
    __shared__ float ybuf[4096];

    if (lane < 32) {
        const size_t pidx = ((size_t)l * 256 + h) * 32 + lane;
        const float dt = __expf(log_dt[l * 256 + h]);
        const float Ar = -__expf(log_A_real[pidx]);
        const float Ai = A_imag[pidx];
        const float er = __expf(Ar * dt);
        float sv, cv;
        __sincosf(Ai * dt, &sv, &cv);
        const float wr = er * cv, wi = er * sv;
        // Ct = (Cr + i Ci) * (w - 1) / A
        const float den = 1.f / (Ar * Ar + Ai * Ai);
        const float nr = wr - 1.f, ni = wi;
        const float qr = (nr * Ar + ni * Ai) * den;
        const float qi = (ni * Ar - nr * Ai) * den;
        const float cr = C_r[pidx], ci = C_i[pidx];
        wsh[lane] = make_float2(wr, wi);
        csh[lane] = make_float2(cr * qr - ci * qi, cr * qi + ci * qr);
    }
    if (lane == 0) dsh = Dsk[l * 256 + h];
    __syncthreads();

    const float* zrp = z + ((size_t)b * 512 + h) * 2048 + lane * 32;
    const float* zip = zrp + 256 * 2048;
    float ur[32], ui[32], yr[32], yi[32];
#pragma unroll
    for (int j = 0; j < 8; ++j) {
        *(float4*)&ur[j * 4] = *(const float4*)(zrp + j * 4);
        *(float4*)&ui[j * 4] = *(const float4*)(zip + j * 4);
    }
#pragma unroll
    for (int t = 0; t < 32; ++t) { yr[t] = 0.f; yi[t] = 0.f; }

    for (int n = 0; n < 32; ++n) {
        const float2 w = wsh[n], ct = csh[n];
        // local scan, zero initial state
        float xr = 0.f, xi = 0.f;
#pragma unroll
        for (int t = 0; t < 32; ++t) {
            const float nxr = __builtin_fmaf(w.x, xr, __builtin_fmaf(-w.y, xi, ur[t]));
            const float nxi = __builtin_fmaf(w.x, xi, __builtin_fmaf(w.y, xr, ui[t]));
            xr = nxr; xi = nxi;
            yr[t] += ct.x * xr - ct.y * xi;
            yi[t] += ct.x * xi + ct.y * xr;
        }
        // f = w^32 (5 squarings)
        float fr = w.x, fi = w.y;
#pragma unroll
        for (int s = 0; s < 5; ++s) { const float a2 = fr * fr - fi * fi, b2 = 2.f * fr * fi; fr = a2; fi = b2; }
        // inclusive Hillis-Steele prefix with multiplier f over chunk-final states
        float qrv = xr, qiv = xi, pr = fr, pi = fi;
#pragma unroll
        for (int s = 0; s < 6; ++s) {
            const int d = 1 << s;
            const float sr = __shfl_up(qrv, (unsigned)d);
            const float si = __shfl_up(qiv, (unsigned)d);
            if (lane >= d) {
                qrv += pr * sr - pi * si;
                qiv += pr * si + pi * sr;
            }
            const float a2 = pr * pr - pi * pi, b2 = 2.f * pr * pi;
            pr = a2; pi = b2;
        }
        // carry into this chunk = Q[lane-1]
        float vr = __shfl_up(qrv, 1u);
        float vi = __shfl_up(qiv, 1u);
        if (lane == 0) { vr = 0.f; vi = 0.f; }
        // carry correction: x[c*32+t] += w^{t+1} * C
#pragma unroll
        for (int t = 0; t < 32; ++t) {
            const float a2 = w.x * vr - w.y * vi;
            const float b2 = w.x * vi + w.y * vr;
            vr = a2; vi = b2;
            yr[t] += ct.x * vr - ct.y * vi;
            yi[t] += ct.x * vi + ct.y * vr;
        }
    }
    // D-skip + gelu, stage to LDS for coalesced writeback
    const float dv = dsh;
#pragma unroll
    for (int t = 0; t < 32; ++t) {
        ybuf[lane * 32 + t]        = gelu_tanh(yr[t] + dv * ur[t]);
        ybuf[2048 + lane * 32 + t] = gelu_tanh(yi[t] + dv * ui[t]);
    }
    __syncthreads();
    float* yrp = y + ((size_t)b * 512 + h) * 2048;
    float* yip = yrp + 256 * 2048;
#pragma unroll
    for (int j = 0; j < 32; ++j) {
        yrp[j * 64 + lane] = ybuf[j * 64 + lane];
        yip[j * 64 + lane] = ybuf[2048 + j * 64 + lane];
    }
}

// ---------------- residual + channel LayerNorm ----------------
// grid: (T/32, B, 2 comps). z <- LN(z + o) over 256 channels per (b,t,comp).
__global__ __launch_bounds__(256) void ln_k(
    const float* __restrict__ o, float* __restrict__ z,
    const float* __restrict__ gamr, const float* __restrict__ gami,
    const float* __restrict__ betr, const float* __restrict__ beti, int l)
{
    const int tt = blockIdx.x, b = blockIdx.y, comp = blockIdx.z;
    const int tid = threadIdx.x;
    const int tloc = tid & 31, gq = tid >> 5;
    __shared__ float tile[256][33];
    __shared__ float red[2][8][32];
    __shared__ float stat[2][32];
    const int t0 = tt * 32;
    const size_t base = ((size_t)b * 512 + comp * 256) * 2048 + t0 + tloc;

#pragma unroll 4
    for (int j = 0; j < 32; ++j) {
        const int g = j * 8 + gq;
        const size_t idx = base + (size_t)g * 2048;
        tile[g][tloc] = o[idx] + z[idx];
    }
    __syncthreads();
    float s = 0.f, sq = 0.f;
#pragma unroll 4
    for (int g2 = 0; g2 < 32; ++g2) {
        const float v = tile[gq * 32 + g2][tloc];
        s += v; sq += v * v;
    }
    red[0][gq][tloc] = s; red[1][gq][tloc] = sq;
    __syncthreads();
    if (tid < 32) {
        float S = 0.f, SQ = 0.f;
#pragma unroll
        for (int q = 0; q < 8; ++q) { S += red[0][q][tid]; SQ += red[1][q][tid]; }
        const float m = S * (1.f / 256.f);
        const float var = SQ * (1.f / 256.f) - m * m;
        stat[0][tid] = m;
        stat[1][tid] = rsqrtf(var + 1e-5f);
    }
    __syncthreads();
    const float* gam = (comp ? gami : gamr) + l * 256;
    const float* bet = (comp ? beti : betr) + l * 256;
    const float m = stat[0][tloc], rs = stat[1][tloc];
#pragma unroll 4
    for (int j = 0; j < 32; ++j) {
        const int g = j * 8 + gq;
        z[base + (size_t)g * 2048] = (tile[g][tloc] - m) * rs * gam[g] + bet[g];
    }
}

extern "C" void kernel_launch(void* const* d_in, const int* in_sizes, int n_in,
                              void* d_out, int out_size, void* d_ws, size_t ws_size,
                              hipStream_t stream)
{
    const float* x        = (const float*)d_in[0];
    const float* enc_Wr   = (const float*)d_in[1];
    const float* enc_Wi   = (const float*)d_in[2];
    const float* enc_br   = (const float*)d_in[3];
    const float* enc_bi   = (const float*)d_in[4];
    const float* log_dt   = (const float*)d_in[5];
    const float* log_A_r  = (const float*)d_in[6];
    const float* A_imag   = (const float*)d_in[7];
    const float* C_r      = (const float*)d_in[8];
    const float* C_i      = (const float*)d_in[9];
    const float* Dp       = (const float*)d_in[10];
    const float* out_Wr   = (const float*)d_in[11];
    const float* out_Wi   = (const float*)d_in[12];
    const float* out_br   = (const float*)d_in[13];
    const float* out_bi   = (const float*)d_in[14];
    const float* ln_gr    = (const float*)d_in[15];
    const float* ln_gi    = (const float*)d_in[16];
    const float* ln_br    = (const float*)d_in[17];
    const float* ln_bi    = (const float*)d_in[18];
    const float* dec_Wr   = (const float*)d_in[19];
    const float* dec_Wi   = (const float*)d_in[20];
    const float* dec_br   = (const float*)d_in[21];
    const float* dec_bi   = (const float*)d_in[22];

    // workspace layout (floats)
    float* ws    = (float*)d_ws;
    float* z     = ws;                      // 8*512*2048 = 8388608
    float* A_enc = ws + 8388608;            // 512*1028   = 526336
    float* A_lay = A_enc + 526336;          // 4*512*512  = 1048576
    float* A_dec = A_lay + 1048576;         // 1028*512   = 526336
    float* b_enc = A_dec + 526336;          // 512
    float* b_lay = b_enc + 512;             // 4*512
    float* b_dec = b_lay + 2048;            // 1028
    // d_out (16.84M floats) doubles as scratch: o (8.39M) + y (8.39M)
    float* o = (float*)d_out;
    float* y = o + 8388608;

    // ---- build stacked real-rep weights + biases ----
    build_stack_k<<<2056, 256, 0, stream>>>(enc_Wr, enc_Wi, A_enc, 256, 514);
    for (int l = 0; l < 4; ++l)
        build_stack_k<<<1024, 256, 0, stream>>>(out_Wr + (size_t)l * 65536,
                                                out_Wi + (size_t)l * 65536,
                                                A_lay + (size_t)l * 262144, 256, 256);
    build_stack_k<<<2056, 256, 0, stream>>>(dec_Wr, dec_Wi, A_dec, 514, 256);
    build_bias_k<<<2, 256, 0, stream>>>(enc_br, enc_bi, b_enc, 256);
    for (int l = 0; l < 4; ++l)
        build_bias_k<<<2, 256, 0, stream>>>(out_br + l * 256, out_bi + l * 256,
                                            b_lay + l * 512, 256);
    build_bias_k<<<5, 256, 0, stream>>>(dec_br, dec_bi, b_dec, 514);

    // ---- encoder: x -> z ----
    cgemm_k<0><<<dim3(4, 16, 8), 256, 0, stream>>>(A_enc, b_enc, x, z, 512, 1028);

    // ---- layers ----
    for (int l = 0; l < 4; ++l) {
        s4scan_k<<<dim3(256, 8), 64, 0, stream>>>(z, y, log_dt, log_A_r, A_imag,
                                                  C_r, C_i, Dp, l);
        cgemm_k<1><<<dim3(4, 16, 8), 256, 0, stream>>>(A_lay + (size_t)l * 262144,
                                                       b_lay + l * 512, y, o, 512, 512);
        ln_k<<<dim3(64, 8, 2), 256, 0, stream>>>(o, z, ln_gr, ln_gi, ln_br, ln_bi, l);
    }

    // ---- decoder: z -> d_out (interleaved), overwrites every output element ----
    cgemm_k<2><<<dim3(9, 16, 8), 256, 0, stream>>>(A_dec, b_dec, z, (float*)d_out, 1028, 512);
}

// Round 2
// 792.210 us; speedup vs baseline: 2.2226x; 2.2226x over previous
//
#include <hip/hip_runtime.h>
#include <cstddef>
#include <cstdint>

// B=8, C=2, Hf=257, T=2048, D_IN=514, DM=256, NL=4, N=32
// Activations: fp32 planes (b, 2*DM=512, T). GEMMs run bf16 MFMA with
// k-major bf16 activation copies (b, T, Kp).

typedef __attribute__((ext_vector_type(8))) short short8;
typedef __attribute__((ext_vector_type(4))) float float4v;

__device__ __forceinline__ unsigned short f2bf(float f) {
    union { float f; unsigned u; } v; v.f = f;
    const unsigned r = v.u + 0x7fffu + ((v.u >> 16) & 1u);  // RNE
    return (unsigned short)(r >> 16);
}

__device__ __forceinline__ float gelu_tanh(float x) {
    const float x3 = x * x * x;
    const float v  = 0.7978845608028654f * (x + 0.044715f * x3);
    const float e  = __expf(2.f * v);
    const float th = 1.f - 2.f / (e + 1.f);
    return 0.5f * x * (1.f + th);
}

#define ASYNC_COPY16(gp, lp) __builtin_amdgcn_global_load_lds( \
    (const __attribute__((address_space(1))) unsigned int*)(gp), \
    (__attribute__((address_space(3))) unsigned int*)(lp), 16, 0, 0)

// ---------- builders: bf16 real-rep of complex weights, padded ----------
// rows m<G: [blk0=Wr | blk1=-Wi], rows G..2G: [Wi | Wr]; zero pads elsewhere.
__global__ __launch_bounds__(256) void buildw_k(
    const float* __restrict__ Wr, const float* __restrict__ Wi,
    unsigned short* __restrict__ A, int G, int H, int Hoff, int Kp, int Mp)
{
    const long long i = (long long)blockIdx.x * 256 + threadIdx.x;
    if (i >= (long long)Mp * Kp) return;
    const int m = (int)(i / Kp), k = (int)(i % Kp);
    float val = 0.f;
    if (m < 2 * G) {
        const int ri = m >= G;
        const int g = m - ri * G;
        const int blk = k >= Hoff;
        const int hh = k - blk * Hoff;
        if (hh < H) {
            const float wr = Wr[(size_t)g * H + hh];
            const float wi = Wi[(size_t)g * H + hh];
            val = ri ? (blk ? wr : wi) : (blk ? -wi : wr);
        }
    }
    A[i] = f2bf(val);
}

__global__ __launch_bounds__(256) void build_bias_k(
    const float* __restrict__ br, const float* __restrict__ bi,
    float* __restrict__ bias, int G)
{
    const int i = blockIdx.x * 256 + threadIdx.x;
    if (i < G) bias[i] = br[i];
    else if (i < 2 * G) bias[i] = bi[i - G];
}

// ---------- encoder input pack: x (b,514,T,2) fp32 -> xp (b,T,1056) bf16 ----------
// k-layout: [0,514)=real, [528,1042)=imag, pads zero.
__global__ __launch_bounds__(256) void packx_k(const float* __restrict__ x,
                                               unsigned short* __restrict__ xp)
{
    const int t0 = blockIdx.x * 64, d0 = blockIdx.y * 64, b = blockIdx.z;
    __shared__ unsigned short tr_[64][72];
    __shared__ unsigned short ti_[64][72];
    const int tid = threadIdx.x;
    const int tp = tid & 31, dl0 = tid >> 5;
#pragma unroll
    for (int p = 0; p < 8; ++p) {
        const int d = dl0 + p * 8;
        const int gd = d0 + d;
        float4 v = make_float4(0.f, 0.f, 0.f, 0.f);
        if (gd < 514) v = *(const float4*)(x + (((size_t)b * 514 + gd) * 2048 + t0 + tp * 2) * 2);
        tr_[tp * 2 + 0][d] = f2bf(v.x); ti_[tp * 2 + 0][d] = f2bf(v.y);
        tr_[tp * 2 + 1][d] = f2bf(v.z); ti_[tp * 2 + 1][d] = f2bf(v.w);
    }
    __syncthreads();
    const int dc = tid & 7;
    const int kloc = d0 + dc * 8;
    if (kloc < 528) {
#pragma unroll
        for (int p = 0; p < 2; ++p) {
            const int t = (tid >> 3) + p * 32;
            const size_t rowb = ((size_t)b * 2048 + t0 + t) * 1056;
            *(short8*)&xp[rowb + kloc]       = *(const short8*)&tr_[t][dc * 8];
            *(short8*)&xp[rowb + 528 + kloc] = *(const short8*)&ti_[t][dc * 8];
        }
    }
}

// ---------- transpose planes (b,512,T) -> k-major (b,T,512) bf16 ----------
template<int SRC32>
__global__ __launch_bounds__(256) void tr_k(const void* __restrict__ src,
                                            unsigned short* __restrict__ dst)
{
    const int t0 = blockIdx.x * 64, k0 = blockIdx.y * 64, b = blockIdx.z;
    __shared__ unsigned short tile[64][72];
    const int tid = threadIdx.x;
    if (SRC32) {
        const float* sf = (const float*)src;
        const int tp = tid & 31, kl0 = tid >> 5;
#pragma unroll
        for (int p = 0; p < 8; ++p) {
            const int kl = kl0 + p * 8;
            const float2 v = *(const float2*)(sf + ((size_t)b * 512 + k0 + kl) * 2048 + t0 + tp * 2);
            tile[tp * 2 + 0][kl] = f2bf(v.x);
            tile[tp * 2 + 1][kl] = f2bf(v.y);
        }
    } else {
        const unsigned short* su = (const unsigned short*)src;
        const int toct = tid & 7, kl0 = tid >> 3;
#pragma unroll
        for (int p = 0; p < 2; ++p) {
            const int kl = kl0 + p * 32;
            const short8 v = *(const short8*)(su + ((size_t)b * 512 + k0 + kl) * 2048 + t0 + toct * 8);
#pragma unroll
            for (int j = 0; j < 8; ++j) tile[toct * 8 + j][kl] = ((const unsigned short*)&v)[j];
        }
    }
    __syncthreads();
    const int dc = tid & 7;
#pragma unroll
    for (int p = 0; p < 2; ++p) {
        const int t = (tid >> 3) + p * 32;
        *(short8*)&dst[((size_t)b * 2048 + t0 + t) * 512 + k0 + dc * 8] = *(const short8*)&tile[t][dc * 8];
    }
}

// ---------- bf16 MFMA GEMM: out(b,M,T) = A(Mp x Kp) * Bm(b,T,Kp)^T + bias ----------
// 128x128 tile, BK=32, 4 waves (2x2 of 64x64), 16x16x32 bf16 MFMA.
// MODE 0: fp32 plane out (b,512,T). MODE 1: decoder interleaved (b,514,T,2), guard m<M.
template<int MODE>
__global__ __launch_bounds__(256, 2) void mgemm_k(
    const unsigned short* __restrict__ A, const float* __restrict__ bias,
    const unsigned short* __restrict__ Bm, float* __restrict__ out,
    int M, int Kp)
{
    __shared__ unsigned short As[4096];  // [m 0..127][k 0..31]
    __shared__ unsigned short Bs[4096];  // [t 0..127][k 0..31]
    const int tid = threadIdx.x;
    const int w = tid >> 6, lane = tid & 63;
    const int m0 = blockIdx.x * 128, t0 = blockIdx.y * 128, b = blockIdx.z;
    const int wm = w & 1, wn = w >> 1;

    const unsigned short* Ab = A + (size_t)m0 * Kp;
    const unsigned short* Bb = Bm + ((size_t)b * 2048 + t0) * Kp;

    const int c0 = w * 64 + lane;             // staging chunk ids (16 B each)
    const int r0 = c0 >> 2, q0 = (c0 & 3) * 8;
    const int c1 = c0 + 256;
    const int r1 = c1 >> 2, q1 = (c1 & 3) * 8;
    unsigned short* As0 = &As[(size_t)(w * 64) * 8];
    unsigned short* As1 = &As[(size_t)(w * 64 + 256) * 8];
    unsigned short* Bs0 = &Bs[(size_t)(w * 64) * 8];
    unsigned short* Bs1 = &Bs[(size_t)(w * 64 + 256) * 8];

    float4v acc[4][4];
#pragma unroll
    for (int i = 0; i < 4; ++i)
#pragma unroll
        for (int j = 0; j < 4; ++j) acc[i][j] = (float4v){0.f, 0.f, 0.f, 0.f};

    const int arow = wm * 64 + (lane & 15);
    const int brow = wn * 64 + (lane & 15);
    const int kq = (lane >> 4) * 8;

    for (int k0 = 0; k0 < Kp; k0 += 32) {
        ASYNC_COPY16(Ab + (size_t)r0 * Kp + k0 + q0, As0);
        ASYNC_COPY16(Ab + (size_t)r1 * Kp + k0 + q1, As1);
        ASYNC_COPY16(Bb + (size_t)r0 * Kp + k0 + q0, Bs0);
        ASYNC_COPY16(Bb + (size_t)r1 * Kp + k0 + q1, Bs1);
        __syncthreads();
        short8 af[4], bf[4];
#pragma unroll
        for (int i = 0; i < 4; ++i) af[i] = *(const short8*)&As[(arow + i * 16) * 32 + kq];
#pragma unroll
        for (int j = 0; j < 4; ++j) bf[j] = *(const short8*)&Bs[(brow + j * 16) * 32 + kq];
#pragma unroll
        for (int i = 0; i < 4; ++i)
#pragma unroll
            for (int j = 0; j < 4; ++j)
                acc[i][j] = __builtin_amdgcn_mfma_f32_16x16x32_bf16(af[i], bf[j], acc[i][j], 0, 0, 0);
        __syncthreads();
    }

    const int col = lane & 15;
    const int rq = (lane >> 4) * 4;
#pragma unroll
    for (int i = 0; i < 4; ++i) {
        const int mloc = wm * 64 + i * 16 + rq;
#pragma unroll
        for (int r = 0; r < 4; ++r) {
            const int m = m0 + mloc + r;
            if (MODE == 1 && m >= M) continue;
            const float bs = bias[m];
#pragma unroll
            for (int j = 0; j < 4; ++j) {
                const int t = t0 + wn * 64 + j * 16 + col;
                const float vv = acc[i][j][r] + bs;
                if (MODE == 0) {
                    out[((size_t)b * 512 + m) * 2048 + t] = vv;
                } else {
                    const int comp = m >= 514;
                    const int g = m - 514 * comp;
                    out[(((size_t)b * 514 + g) * 2048 + t) * 2 + comp] = vv;
                }
            }
        }
    }
}

// ---------- S4D diagonal SSM scan + D-skip + gelu -> bf16 planes ----------
// One wave per (b,h). Lane c owns t in [c*32, c*32+32). Pass1: local final
// states; wave prefix (multiplier w^32) -> carries; pass2: carry-init scan
// with output accumulation (12 fma/step total vs 16 before).
__global__ __launch_bounds__(64) void s4scan_k(
    const float* __restrict__ z, unsigned short* __restrict__ y,
    const float* __restrict__ log_dt, const float* __restrict__ log_A_real,
    const float* __restrict__ A_imag, const float* __restrict__ C_r,
    const float* __restrict__ C_i, const float* __restrict__ Dsk, int l)
{
    const int h = blockIdx.x, b = blockIdx.y;
    const int lane = threadIdx.x;
    __shared__ float2 wsh[32], csh[32];
    __shared__ float dsh;
    __shared__ unsigned short ybuf[2 * 2176];   // [zone][lane][34] padded

    if (lane < 32) {
        const size_t pidx = ((size_t)l * 256 + h) * 32 + lane;
        const float dt = __expf(log_dt[l * 256 + h]);
        const float Ar = -__expf(log_A_real[pidx]);
        const float Ai = A_imag[pidx];
        const float er = __expf(Ar * dt);
        float sv, cv;
        __sincosf(Ai * dt, &sv, &cv);
        const float wr = er * cv, wi = er * sv;
        const float den = 1.f / (Ar * Ar + Ai * Ai);
        const float nr = wr - 1.f, ni = wi;
        const float qr = (nr * Ar + ni * Ai) * den;
        const float qi = (ni * Ar - nr * Ai) * den;
        const float cr = C_r[pidx], ci = C_i[pidx];
        wsh[lane] = make_float2(wr, wi);
        csh[lane] = make_float2(cr * qr - ci * qi, cr * qi + ci * qr);
    }
    if (lane == 0) dsh = Dsk[l * 256 + h];
    __syncthreads();

    const float* zrp = z + ((size_t)b * 512 + h) * 2048 + lane * 32;
    const float* zip = zrp + 256 * 2048;
    float ur[32], ui[32], yr[32], yi[32];
#pragma unroll
    for (int j = 0; j < 8; ++j) {
        *(float4*)&ur[j * 4] = *(const float4*)(zrp + j * 4);
        *(float4*)&ui[j * 4] = *(const float4*)(zip + j * 4);
    }
#pragma unroll
    for (int t = 0; t < 32; ++t) { yr[t] = 0.f; yi[t] = 0.f; }

    for (int n = 0; n < 32; ++n) {
        const float2 w = wsh[n], ct = csh[n];
        // pass 1: chunk-local final state (zero init)
        float xr = 0.f, xi = 0.f;
#pragma unroll
        for (int t = 0; t < 32; ++t) {
            const float nxr = __builtin_fmaf(w.x, xr, __builtin_fmaf(-w.y, xi, ur[t]));
            const float nxi = __builtin_fmaf(w.x, xi, __builtin_fmaf(w.y, xr, ui[t]));
            xr = nxr; xi = nxi;
        }
        // f = w^32
        float fr = w.x, fi = w.y;
#pragma unroll
        for (int s = 0; s < 5; ++s) { const float a2 = fr * fr - fi * fi, b2 = 2.f * fr * fi; fr = a2; fi = b2; }
        // inclusive prefix over chunk-final states with multiplier f
        float qrv = xr, qiv = xi, pr = fr, pi = fi;
#pragma unroll
        for (int s = 0; s < 6; ++s) {
            const int d = 1 << s;
            const float sr = __shfl_up(qrv, (unsigned)d);
            const float si = __shfl_up(qiv, (unsigned)d);
            if (lane >= d) {
                qrv += pr * sr - pi * si;
                qiv += pr * si + pi * sr;
            }
            const float a2 = pr * pr - pi * pi, b2 = 2.f * pr * pi;
            pr = a2; pi = b2;
        }
        float vr = __shfl_up(qrv, 1u);
        float vi = __shfl_up(qiv, 1u);
        if (lane == 0) { vr = 0.f; vi = 0.f; }
        // pass 2: carry-init scan + output accumulation
        float sr2 = vr, si2 = vi;
#pragma unroll
        for (int t = 0; t < 32; ++t) {
            const float nsr = __builtin_fmaf(w.x, sr2, __builtin_fmaf(-w.y, si2, ur[t]));
            const float nsi = __builtin_fmaf(w.x, si2, __builtin_fmaf(w.y, sr2, ui[t]));
            sr2 = nsr; si2 = nsi;
            yr[t] += ct.x * sr2 - ct.y * si2;
            yi[t] += ct.x * si2 + ct.y * sr2;
        }
    }
    const float dv = dsh;
#pragma unroll
    for (int t = 0; t < 32; ++t) {
        ybuf[lane * 34 + t]        = f2bf(gelu_tanh(yr[t] + dv * ur[t]));
        ybuf[2176 + lane * 34 + t] = f2bf(gelu_tanh(yi[t] + dv * ui[t]));
    }
    __syncthreads();
    unsigned short* yrp = y + ((size_t)b * 512 + h) * 2048;
    unsigned short* yip = yrp + 256 * 2048;
#pragma unroll
    for (int j = 0; j < 32; ++j) {
        const int tg = j * 64 + lane;
        const int c = tg >> 5, pos = tg & 31;
        yrp[tg] = ybuf[c * 34 + pos];
        yip[tg] = ybuf[2176 + c * 34 + pos];
    }
}

// ---------- residual + channel LayerNorm (fp32 planes) ----------
__global__ __launch_bounds__(256) void ln_k(
    const float* __restrict__ o, float* __restrict__ z,
    const float* __restrict__ gamr, const float* __restrict__ gami,
    const float* __restrict__ betr, const float* __restrict__ beti, int l)
{
    const int tt = blockIdx.x, b = blockIdx.y, comp = blockIdx.z;
    const int tid = threadIdx.x;
    const int tloc = tid & 31, gq = tid >> 5;
    __shared__ float tile[256][33];
    __shared__ float red[2][8][32];
    __shared__ float stat[2][32];
    const int t0 = tt * 32;
    const size_t base = ((size_t)b * 512 + comp * 256) * 2048 + t0 + tloc;

#pragma unroll 4
    for (int j = 0; j < 32; ++j) {
        const int g = j * 8 + gq;
        const size_t idx = base + (size_t)g * 2048;
        tile[g][tloc] = o[idx] + z[idx];
    }
    __syncthreads();
    float s = 0.f, sq = 0.f;
#pragma unroll 4
    for (int g2 = 0; g2 < 32; ++g2) {
        const float v = tile[gq * 32 + g2][tloc];
        s += v; sq += v * v;
    }
    red[0][gq][tloc] = s; red[1][gq][tloc] = sq;
    __syncthreads();
    if (tid < 32) {
        float S = 0.f, SQ = 0.f;
#pragma unroll
        for (int q = 0; q < 8; ++q) { S += red[0][q][tid]; SQ += red[1][q][tid]; }
        const float m = S * (1.f / 256.f);
        const float var = SQ * (1.f / 256.f) - m * m;
        stat[0][tid] = m;
        stat[1][tid] = rsqrtf(var + 1e-5f);
    }
    __syncthreads();
    const float* gam = (comp ? gami : gamr) + l * 256;
    const float* bet = (comp ? beti : betr) + l * 256;
    const float m = stat[0][tloc], rs = stat[1][tloc];
#pragma unroll 4
    for (int j = 0; j < 32; ++j) {
        const int g = j * 8 + gq;
        z[base + (size_t)g * 2048] = (tile[g][tloc] - m) * rs * gam[g] + bet[g];
    }
}

extern "C" void kernel_launch(void* const* d_in, const int* in_sizes, int n_in,
                              void* d_out, int out_size, void* d_ws, size_t ws_size,
                              hipStream_t stream)
{
    const float* x        = (const float*)d_in[0];
    const float* enc_Wr   = (const float*)d_in[1];
    const float* enc_Wi   = (const float*)d_in[2];
    const float* enc_br   = (const float*)d_in[3];
    const float* enc_bi   = (const float*)d_in[4];
    const float* log_dt   = (const float*)d_in[5];
    const float* log_A_r  = (const float*)d_in[6];
    const float* A_imag   = (const float*)d_in[7];
    const float* C_r      = (const float*)d_in[8];
    const float* C_i      = (const float*)d_in[9];
    const float* Dp       = (const float*)d_in[10];
    const float* out_Wr   = (const float*)d_in[11];
    const float* out_Wi   = (const float*)d_in[12];
    const float* out_br   = (const float*)d_in[13];
    const float* out_bi   = (const float*)d_in[14];
    const float* ln_gr    = (const float*)d_in[15];
    const float* ln_gi    = (const float*)d_in[16];
    const float* ln_br    = (const float*)d_in[17];
    const float* ln_bi    = (const float*)d_in[18];
    const float* dec_Wr   = (const float*)d_in[19];
    const float* dec_Wi   = (const float*)d_in[20];
    const float* dec_br   = (const float*)d_in[21];
    const float* dec_bi   = (const float*)d_in[22];

    // ---- workspace layout (bytes) ----
    uint8_t* W = (uint8_t*)d_ws;
    float* z             = (float*)W;                       // 33,554,432
    unsigned short* zp   = (unsigned short*)(W + 33554432); // 16,777,216
    unsigned short* A_enc= (unsigned short*)(W + 50331648); // 512x1056x2  = 1,081,344
    unsigned short* A_lay= (unsigned short*)(W + 51412992); // 4x512x512x2 = 2,097,152
    unsigned short* A_dec= (unsigned short*)(W + 53510144); // 1152x512x2  = 1,179,648
    float* b_enc         = (float*)(W + 54689792);          // 512 f
    float* b_lay         = (float*)(W + 54691840);          // 2048 f
    float* b_dec         = (float*)(W + 54700032);          // 1028 f

    // ---- d_out doubles as scratch (67.37 MB total) ----
    float* o            = (float*)d_out;                                   // 33,554,432
    unsigned short* y   = (unsigned short*)((uint8_t*)d_out + 33554432);   // 16,777,216
    unsigned short* yp  = (unsigned short*)((uint8_t*)d_out + 50331648);   // 16,777,216
    unsigned short* xp  = (unsigned short*)d_out;  // 34,603,008; dead after encoder GEMM

    // ---- build weights/biases ----
    buildw_k<<<2112, 256, 0, stream>>>(enc_Wr, enc_Wi, A_enc, 256, 514, 528, 1056, 512);
    for (int l = 0; l < 4; ++l)
        buildw_k<<<1024, 256, 0, stream>>>(out_Wr + (size_t)l * 65536, out_Wi + (size_t)l * 65536,
                                           A_lay + (size_t)l * 262144, 256, 256, 256, 512, 512);
    buildw_k<<<2304, 256, 0, stream>>>(dec_Wr, dec_Wi, A_dec, 514, 256, 256, 512, 1152);
    build_bias_k<<<2, 256, 0, stream>>>(enc_br, enc_bi, b_enc, 256);
    for (int l = 0; l < 4; ++l)
        build_bias_k<<<2, 256, 0, stream>>>(out_br + l * 256, out_bi + l * 256, b_lay + l * 512, 256);
    build_bias_k<<<5, 256, 0, stream>>>(dec_br, dec_bi, b_dec, 514);

    // ---- encoder: pack x -> xp, GEMM -> z ----
    packx_k<<<dim3(32, 9, 8), 256, 0, stream>>>(x, xp);
    mgemm_k<0><<<dim3(4, 16, 8), 256, 0, stream>>>(A_enc, b_enc, xp, z, 512, 1056);

    // ---- layers ----
    for (int l = 0; l < 4; ++l) {
        s4scan_k<<<dim3(256, 8), 64, 0, stream>>>(z, y, log_dt, log_A_r, A_imag, C_r, C_i, Dp, l);
        tr_k<0><<<dim3(32, 8, 8), 256, 0, stream>>>(y, yp);
        mgemm_k<0><<<dim3(4, 16, 8), 256, 0, stream>>>(A_lay + (size_t)l * 262144,
                                                       b_lay + l * 512, yp, o, 512, 512);
        ln_k<<<dim3(64, 8, 2), 256, 0, stream>>>(o, z, ln_gr, ln_gi, ln_br, ln_bi, l);
    }

    // ---- decoder: z -> zp, GEMM -> d_out interleaved (overwrites all scratch) ----
    tr_k<1><<<dim3(32, 8, 8), 256, 0, stream>>>(z, zp);
    mgemm_k<1><<<dim3(9, 16, 8), 256, 0, stream>>>(A_dec, b_dec, zp, (float*)d_out, 1028, 512);
}

// Round 3
// 723.470 us; speedup vs baseline: 2.4338x; 1.0950x over previous
//
#include <hip/hip_runtime.h>
#include <cstddef>
#include <cstdint>

// B=8, C=2, Hf=257, T=2048, D_IN=514, DM=256, NL=4, N=32
// Activations: fp32 planes (b, 2*DM=512, T). GEMMs run bf16 MFMA with
// k-major bf16 activation copies (b, T, Kp).

typedef __attribute__((ext_vector_type(8))) short short8;
typedef __attribute__((ext_vector_type(4))) float float4v;

__device__ __forceinline__ unsigned short f2bf(float f) {
    union { float f; unsigned u; } v; v.f = f;
    const unsigned r = v.u + 0x7fffu + ((v.u >> 16) & 1u);  // RNE
    return (unsigned short)(r >> 16);
}

__device__ __forceinline__ float gelu_tanh(float x) {
    const float x3 = x * x * x;
    const float v  = 0.7978845608028654f * (x + 0.044715f * x3);
    const float e  = __expf(2.f * v);
    const float th = 1.f - 2.f / (e + 1.f);
    return 0.5f * x * (1.f + th);
}

#define ASYNC_COPY16(gp, lp) __builtin_amdgcn_global_load_lds( \
    (const __attribute__((address_space(1))) unsigned int*)(gp), \
    (__attribute__((address_space(3))) unsigned int*)(lp), 16, 0, 0)

// ---------- builders: bf16 real-rep of complex weights, padded ----------
__global__ __launch_bounds__(256) void buildw_k(
    const float* __restrict__ Wr, const float* __restrict__ Wi,
    unsigned short* __restrict__ A, int G, int H, int Hoff, int Kp, int Mp)
{
    const long long i = (long long)blockIdx.x * 256 + threadIdx.x;
    if (i >= (long long)Mp * Kp) return;
    const int m = (int)(i / Kp), k = (int)(i % Kp);
    float val = 0.f;
    if (m < 2 * G) {
        const int ri = m >= G;
        const int g = m - ri * G;
        const int blk = k >= Hoff;
        const int hh = k - blk * Hoff;
        if (hh < H) {
            const float wr = Wr[(size_t)g * H + hh];
            const float wi = Wi[(size_t)g * H + hh];
            val = ri ? (blk ? wr : wi) : (blk ? -wi : wr);
        }
    }
    A[i] = f2bf(val);
}

__global__ __launch_bounds__(256) void build_bias_k(
    const float* __restrict__ br, const float* __restrict__ bi,
    float* __restrict__ bias, int G)
{
    const int i = blockIdx.x * 256 + threadIdx.x;
    if (i < G) bias[i] = br[i];
    else if (i < 2 * G) bias[i] = bi[i - G];
}

// ---------- encoder input pack: x (b,514,T,2) fp32 -> xp (b,T,1056) bf16 ----------
__global__ __launch_bounds__(256) void packx_k(const float* __restrict__ x,
                                               unsigned short* __restrict__ xp)
{
    const int t0 = blockIdx.x * 64, d0 = blockIdx.y * 64, b = blockIdx.z;
    __shared__ unsigned short tr_[64][72];
    __shared__ unsigned short ti_[64][72];
    const int tid = threadIdx.x;
    const int tp = tid & 31, dl0 = tid >> 5;
#pragma unroll
    for (int p = 0; p < 8; ++p) {
        const int d = dl0 + p * 8;
        const int gd = d0 + d;
        float4 v = make_float4(0.f, 0.f, 0.f, 0.f);
        if (gd < 514) v = *(const float4*)(x + (((size_t)b * 514 + gd) * 2048 + t0 + tp * 2) * 2);
        tr_[tp * 2 + 0][d] = f2bf(v.x); ti_[tp * 2 + 0][d] = f2bf(v.y);
        tr_[tp * 2 + 1][d] = f2bf(v.z); ti_[tp * 2 + 1][d] = f2bf(v.w);
    }
    __syncthreads();
    const int dc = tid & 7;
    const int kloc = d0 + dc * 8;
    if (kloc < 528) {
#pragma unroll
        for (int p = 0; p < 2; ++p) {
            const int t = (tid >> 3) + p * 32;
            const size_t rowb = ((size_t)b * 2048 + t0 + t) * 1056;
            *(short8*)&xp[rowb + kloc]       = *(const short8*)&tr_[t][dc * 8];
            *(short8*)&xp[rowb + 528 + kloc] = *(const short8*)&ti_[t][dc * 8];
        }
    }
}

// ---------- transpose planes (b,512,T) -> k-major (b,T,512) bf16 ----------
template<int SRC32>
__global__ __launch_bounds__(256) void tr_k(const void* __restrict__ src,
                                            unsigned short* __restrict__ dst)
{
    const int t0 = blockIdx.x * 64, k0 = blockIdx.y * 64, b = blockIdx.z;
    __shared__ unsigned short tile[64][72];
    const int tid = threadIdx.x;
    if (SRC32) {
        const float* sf = (const float*)src;
        const int tp = tid & 31, kl0 = tid >> 5;
#pragma unroll
        for (int p = 0; p < 8; ++p) {
            const int kl = kl0 + p * 8;
            const float2 v = *(const float2*)(sf + ((size_t)b * 512 + k0 + kl) * 2048 + t0 + tp * 2);
            tile[tp * 2 + 0][kl] = f2bf(v.x);
            tile[tp * 2 + 1][kl] = f2bf(v.y);
        }
    } else {
        const unsigned short* su = (const unsigned short*)src;
        const int toct = tid & 7, kl0 = tid >> 3;
#pragma unroll
        for (int p = 0; p < 2; ++p) {
            const int kl = kl0 + p * 32;
            const short8 v = *(const short8*)(su + ((size_t)b * 512 + k0 + kl) * 2048 + t0 + toct * 8);
#pragma unroll
            for (int j = 0; j < 8; ++j) tile[toct * 8 + j][kl] = ((const unsigned short*)&v)[j];
        }
    }
    __syncthreads();
    const int dc = tid & 7;
#pragma unroll
    for (int p = 0; p < 2; ++p) {
        const int t = (tid >> 3) + p * 32;
        *(short8*)&dst[((size_t)b * 2048 + t0 + t) * 512 + k0 + dc * 8] = *(const short8*)&tile[t][dc * 8];
    }
}

// ---------- bf16 MFMA GEMM: out(b,M,T) = A(Mp x Kp) * Bm(b,T,Kp)^T + bias ----------
template<int MODE>
__global__ __launch_bounds__(256, 2) void mgemm_k(
    const unsigned short* __restrict__ A, const float* __restrict__ bias,
    const unsigned short* __restrict__ Bm, float* __restrict__ out,
    int M, int Kp)
{
    __shared__ unsigned short As[4096];  // [m 0..127][k 0..31]
    __shared__ unsigned short Bs[4096];  // [t 0..127][k 0..31]
    const int tid = threadIdx.x;
    const int w = tid >> 6, lane = tid & 63;
    const int m0 = blockIdx.x * 128, t0 = blockIdx.y * 128, b = blockIdx.z;
    const int wm = w & 1, wn = w >> 1;

    const unsigned short* Ab = A + (size_t)m0 * Kp;
    const unsigned short* Bb = Bm + ((size_t)b * 2048 + t0) * Kp;

    const int c0 = w * 64 + lane;
    const int r0 = c0 >> 2, q0 = (c0 & 3) * 8;
    const int c1 = c0 + 256;
    const int r1 = c1 >> 2, q1 = (c1 & 3) * 8;
    unsigned short* As0 = &As[(size_t)(w * 64) * 8];
    unsigned short* As1 = &As[(size_t)(w * 64 + 256) * 8];
    unsigned short* Bs0 = &Bs[(size_t)(w * 64) * 8];
    unsigned short* Bs1 = &Bs[(size_t)(w * 64 + 256) * 8];

    float4v acc[4][4];
#pragma unroll
    for (int i = 0; i < 4; ++i)
#pragma unroll
        for (int j = 0; j < 4; ++j) acc[i][j] = (float4v){0.f, 0.f, 0.f, 0.f};

    const int arow = wm * 64 + (lane & 15);
    const int brow = wn * 64 + (lane & 15);
    const int kq = (lane >> 4) * 8;

    for (int k0 = 0; k0 < Kp; k0 += 32) {
        ASYNC_COPY16(Ab + (size_t)r0 * Kp + k0 + q0, As0);
        ASYNC_COPY16(Ab + (size_t)r1 * Kp + k0 + q1, As1);
        ASYNC_COPY16(Bb + (size_t)r0 * Kp + k0 + q0, Bs0);
        ASYNC_COPY16(Bb + (size_t)r1 * Kp + k0 + q1, Bs1);
        __syncthreads();
        short8 af[4], bf[4];
#pragma unroll
        for (int i = 0; i < 4; ++i) af[i] = *(const short8*)&As[(arow + i * 16) * 32 + kq];
#pragma unroll
        for (int j = 0; j < 4; ++j) bf[j] = *(const short8*)&Bs[(brow + j * 16) * 32 + kq];
#pragma unroll
        for (int i = 0; i < 4; ++i)
#pragma unroll
            for (int j = 0; j < 4; ++j)
                acc[i][j] = __builtin_amdgcn_mfma_f32_16x16x32_bf16(af[i], bf[j], acc[i][j], 0, 0, 0);
        __syncthreads();
    }

    const int col = lane & 15;
    const int rq = (lane >> 4) * 4;
#pragma unroll
    for (int i = 0; i < 4; ++i) {
        const int mloc = wm * 64 + i * 16 + rq;
#pragma unroll
        for (int r = 0; r < 4; ++r) {
            const int m = m0 + mloc + r;
            if (MODE == 1 && m >= M) continue;
            const float bs = bias[m];
#pragma unroll
            for (int j = 0; j < 4; ++j) {
                const int t = t0 + wn * 64 + j * 16 + col;
                const float vv = acc[i][j][r] + bs;
                if (MODE == 0) {
                    out[((size_t)b * 512 + m) * 2048 + t] = vv;
                } else {
                    const int comp = m >= 514;
                    const int g = m - 514 * comp;
                    out[(((size_t)b * 514 + g) * 2048 + t) * 2 + comp] = vv;
                }
            }
        }
    }
}

// ---------- S4D diagonal SSM scan + D-skip + gelu -> bf16 planes ----------
// Block = 256 threads (4 waves) per (b,h). Wave wv owns modes 8wv..8wv+7;
// lane c owns timesteps [c*32, c*32+32) (same chunking in every wave).
// Partials combined in LDS (4-phase add, stride-34 fp32 = 2-way aliasing only).
// D*u is linear -> folded into wave 0's partial; final phase: gelu + coalesced
// bf16 stores.
__global__ __launch_bounds__(256) void s4scan_k(
    const float* __restrict__ z, unsigned short* __restrict__ y,
    const float* __restrict__ log_dt, const float* __restrict__ log_A_real,
    const float* __restrict__ A_imag, const float* __restrict__ C_r,
    const float* __restrict__ C_i, const float* __restrict__ Dsk, int l)
{
    const int h = blockIdx.x, b = blockIdx.y;
    const int tid = threadIdx.x;
    const int wv = tid >> 6, lane = tid & 63;
    __shared__ float2 wsh[32], csh[32];
    __shared__ float dsh;
    __shared__ float buf[2][64][34];

    if (tid < 32) {
        const size_t pidx = ((size_t)l * 256 + h) * 32 + tid;
        const float dt = __expf(log_dt[l * 256 + h]);
        const float Ar = -__expf(log_A_real[pidx]);
        const float Ai = A_imag[pidx];
        const float er = __expf(Ar * dt);
        float sv, cv;
        __sincosf(Ai * dt, &sv, &cv);
        const float wr = er * cv, wi = er * sv;
        const float den = 1.f / (Ar * Ar + Ai * Ai);
        const float nr = wr - 1.f, ni = wi;
        const float qr = (nr * Ar + ni * Ai) * den;
        const float qi = (ni * Ar - nr * Ai) * den;
        const float cr = C_r[pidx], ci = C_i[pidx];
        wsh[tid] = make_float2(wr, wi);
        csh[tid] = make_float2(cr * qr - ci * qi, cr * qi + ci * qr);
    }
    if (tid == 32) dsh = Dsk[l * 256 + h];
    __syncthreads();

    const float* zrp = z + ((size_t)b * 512 + h) * 2048 + lane * 32;
    const float* zip = zrp + 256 * 2048;
    float ur[32], ui[32], yr[32], yi[32];
#pragma unroll
    for (int j = 0; j < 8; ++j) {
        *(float4*)&ur[j * 4] = *(const float4*)(zrp + j * 4);
        *(float4*)&ui[j * 4] = *(const float4*)(zip + j * 4);
    }
#pragma unroll
    for (int t = 0; t < 32; ++t) { yr[t] = 0.f; yi[t] = 0.f; }

    for (int nn = 0; nn < 8; ++nn) {
        const float2 wm = wsh[wv * 8 + nn], ct = csh[wv * 8 + nn];
        // pass 1: chunk-local final state (zero init)
        float xr = 0.f, xi = 0.f;
#pragma unroll
        for (int t = 0; t < 32; ++t) {
            const float nxr = __builtin_fmaf(wm.x, xr, __builtin_fmaf(-wm.y, xi, ur[t]));
            const float nxi = __builtin_fmaf(wm.x, xi, __builtin_fmaf(wm.y, xr, ui[t]));
            xr = nxr; xi = nxi;
        }
        // f = w^32
        float fr = wm.x, fi = wm.y;
#pragma unroll
        for (int s = 0; s < 5; ++s) { const float a2 = fr * fr - fi * fi, b2 = 2.f * fr * fi; fr = a2; fi = b2; }
        // inclusive wave prefix over chunk-final states with multiplier f
        float qrv = xr, qiv = xi, pr = fr, pi = fi;
#pragma unroll
        for (int s = 0; s < 6; ++s) {
            const int d = 1 << s;
            const float sr = __shfl_up(qrv, (unsigned)d);
            const float si = __shfl_up(qiv, (unsigned)d);
            if (lane >= d) {
                qrv += pr * sr - pi * si;
                qiv += pr * si + pi * sr;
            }
            const float a2 = pr * pr - pi * pi, b2 = 2.f * pr * pi;
            pr = a2; pi = b2;
        }
        float vr = __shfl_up(qrv, 1u);
        float vi = __shfl_up(qiv, 1u);
        if (lane == 0) { vr = 0.f; vi = 0.f; }
        // pass 2: carry-init scan + output accumulation
        float sr2 = vr, si2 = vi;
#pragma unroll
        for (int t = 0; t < 32; ++t) {
            const float nsr = __builtin_fmaf(wm.x, sr2, __builtin_fmaf(-wm.y, si2, ur[t]));
            const float nsi = __builtin_fmaf(wm.x, si2, __builtin_fmaf(wm.y, sr2, ui[t]));
            sr2 = nsr; si2 = nsi;
            yr[t] += ct.x * sr2 - ct.y * si2;
            yi[t] += ct.x * si2 + ct.y * sr2;
        }
    }

    // fold D-skip into wave 0's partial (linear term)
    if (wv == 0) {
        const float dv = dsh;
#pragma unroll
        for (int t = 0; t < 32; ++t) {
            yr[t] = __builtin_fmaf(dv, ur[t], yr[t]);
            yi[t] = __builtin_fmaf(dv, ui[t], yi[t]);
        }
    }

    // 4-phase LDS reduction (float2 ops; stride 34 -> 2-way bank aliasing, free)
#pragma unroll
    for (int ph = 0; ph < 4; ++ph) {
        if (wv == ph) {
            if (ph == 0) {
#pragma unroll
                for (int j = 0; j < 16; ++j) {
                    *(float2*)&buf[0][lane][j * 2] = make_float2(yr[j * 2], yr[j * 2 + 1]);
                    *(float2*)&buf[1][lane][j * 2] = make_float2(yi[j * 2], yi[j * 2 + 1]);
                }
            } else {
#pragma unroll
                for (int j = 0; j < 16; ++j) {
                    float2 a = *(const float2*)&buf[0][lane][j * 2];
                    a.x += yr[j * 2]; a.y += yr[j * 2 + 1];
                    *(float2*)&buf[0][lane][j * 2] = a;
                    float2 bq = *(const float2*)&buf[1][lane][j * 2];
                    bq.x += yi[j * 2]; bq.y += yi[j * 2 + 1];
                    *(float2*)&buf[1][lane][j * 2] = bq;
                }
            }
        }
        __syncthreads();
    }

    // final: gelu + bf16 pack + coalesced stores. Thread tid owns t = tid*8..+8.
    const int chunk = tid >> 2, pos = (tid & 3) * 8;
    unsigned short* yrp = y + ((size_t)b * 512 + h) * 2048 + tid * 8;
    unsigned short* yip = yrp + 256 * 2048;
    {
        short8 vr8, vi8;
#pragma unroll
        for (int j = 0; j < 8; ++j) {
            ((unsigned short*)&vr8)[j] = f2bf(gelu_tanh(buf[0][chunk][pos + j]));
            ((unsigned short*)&vi8)[j] = f2bf(gelu_tanh(buf[1][chunk][pos + j]));
        }
        *(short8*)yrp = vr8;
        *(short8*)yip = vi8;
    }
}

// ---------- residual + channel LayerNorm (fp32 planes) ----------
__global__ __launch_bounds__(256) void ln_k(
    const float* __restrict__ o, float* __restrict__ z,
    const float* __restrict__ gamr, const float* __restrict__ gami,
    const float* __restrict__ betr, const float* __restrict__ beti, int l)
{
    const int tt = blockIdx.x, b = blockIdx.y, comp = blockIdx.z;
    const int tid = threadIdx.x;
    const int tloc = tid & 31, gq = tid >> 5;
    __shared__ float tile[256][33];
    __shared__ float red[2][8][32];
    __shared__ float stat[2][32];
    const int t0 = tt * 32;
    const size_t base = ((size_t)b * 512 + comp * 256) * 2048 + t0 + tloc;

#pragma unroll 4
    for (int j = 0; j < 32; ++j) {
        const int g = j * 8 + gq;
        const size_t idx = base + (size_t)g * 2048;
        tile[g][tloc] = o[idx] + z[idx];
    }
    __syncthreads();
    float s = 0.f, sq = 0.f;
#pragma unroll 4
    for (int g2 = 0; g2 < 32; ++g2) {
        const float v = tile[gq * 32 + g2][tloc];
        s += v; sq += v * v;
    }
    red[0][gq][tloc] = s; red[1][gq][tloc] = sq;
    __syncthreads();
    if (tid < 32) {
        float S = 0.f, SQ = 0.f;
#pragma unroll
        for (int q = 0; q < 8; ++q) { S += red[0][q][tid]; SQ += red[1][q][tid]; }
        const float m = S * (1.f / 256.f);
        const float var = SQ * (1.f / 256.f) - m * m;
        stat[0][tid] = m;
        stat[1][tid] = rsqrtf(var + 1e-5f);
    }
    __syncthreads();
    const float* gam = (comp ? gami : gamr) + l * 256;
    const float* bet = (comp ? beti : betr) + l * 256;
    const float m = stat[0][tloc], rs = stat[1][tloc];
#pragma unroll 4
    for (int j = 0; j < 32; ++j) {
        const int g = j * 8 + gq;
        z[base + (size_t)g * 2048] = (tile[g][tloc] - m) * rs * gam[g] + bet[g];
    }
}

extern "C" void kernel_launch(void* const* d_in, const int* in_sizes, int n_in,
                              void* d_out, int out_size, void* d_ws, size_t ws_size,
                              hipStream_t stream)
{
    const float* x        = (const float*)d_in[0];
    const float* enc_Wr   = (const float*)d_in[1];
    const float* enc_Wi   = (const float*)d_in[2];
    const float* enc_br   = (const float*)d_in[3];
    const float* enc_bi   = (const float*)d_in[4];
    const float* log_dt   = (const float*)d_in[5];
    const float* log_A_r  = (const float*)d_in[6];
    const float* A_imag   = (const float*)d_in[7];
    const float* C_r      = (const float*)d_in[8];
    const float* C_i      = (const float*)d_in[9];
    const float* Dp       = (const float*)d_in[10];
    const float* out_Wr   = (const float*)d_in[11];
    const float* out_Wi   = (const float*)d_in[12];
    const float* out_br   = (const float*)d_in[13];
    const float* out_bi   = (const float*)d_in[14];
    const float* ln_gr    = (const float*)d_in[15];
    const float* ln_gi    = (const float*)d_in[16];
    const float* ln_br    = (const float*)d_in[17];
    const float* ln_bi    = (const float*)d_in[18];
    const float* dec_Wr   = (const float*)d_in[19];
    const float* dec_Wi   = (const float*)d_in[20];
    const float* dec_br   = (const float*)d_in[21];
    const float* dec_bi   = (const float*)d_in[22];

    // ---- workspace layout (bytes) ----
    uint8_t* W = (uint8_t*)d_ws;
    float* z             = (float*)W;                       // 33,554,432
    unsigned short* zp   = (unsigned short*)(W + 33554432); // 16,777,216
    unsigned short* A_enc= (unsigned short*)(W + 50331648); // 512x1056x2  = 1,081,344
    unsigned short* A_lay= (unsigned short*)(W + 51412992); // 4x512x512x2 = 2,097,152
    unsigned short* A_dec= (unsigned short*)(W + 53510144); // 1152x512x2  = 1,179,648
    float* b_enc         = (float*)(W + 54689792);          // 512 f
    float* b_lay         = (float*)(W + 54691840);          // 2048 f
    float* b_dec         = (float*)(W + 54700032);          // 1028 f

    // ---- d_out doubles as scratch (67.37 MB total) ----
    float* o            = (float*)d_out;                                   // 33,554,432
    unsigned short* y   = (unsigned short*)((uint8_t*)d_out + 33554432);   // 16,777,216
    unsigned short* yp  = (unsigned short*)((uint8_t*)d_out + 50331648);   // 16,777,216
    unsigned short* xp  = (unsigned short*)d_out;  // 34,603,008; dead after encoder GEMM

    // ---- build weights/biases ----
    buildw_k<<<2112, 256, 0, stream>>>(enc_Wr, enc_Wi, A_enc, 256, 514, 528, 1056, 512);
    for (int l = 0; l < 4; ++l)
        buildw_k<<<1024, 256, 0, stream>>>(out_Wr + (size_t)l * 65536, out_Wi + (size_t)l * 65536,
                                           A_lay + (size_t)l * 262144, 256, 256, 256, 512, 512);
    buildw_k<<<2304, 256, 0, stream>>>(dec_Wr, dec_Wi, A_dec, 514, 256, 256, 512, 1152);
    build_bias_k<<<2, 256, 0, stream>>>(enc_br, enc_bi, b_enc, 256);
    for (int l = 0; l < 4; ++l)
        build_bias_k<<<2, 256, 0, stream>>>(out_br + l * 256, out_bi + l * 256, b_lay + l * 512, 256);
    build_bias_k<<<5, 256, 0, stream>>>(dec_br, dec_bi, b_dec, 514);

    // ---- encoder: pack x -> xp, GEMM -> z ----
    packx_k<<<dim3(32, 9, 8), 256, 0, stream>>>(x, xp);
    mgemm_k<0><<<dim3(4, 16, 8), 256, 0, stream>>>(A_enc, b_enc, xp, z, 512, 1056);

    // ---- layers ----
    for (int l = 0; l < 4; ++l) {
        s4scan_k<<<dim3(256, 8), 256, 0, stream>>>(z, y, log_dt, log_A_r, A_imag, C_r, C_i, Dp, l);
        tr_k<0><<<dim3(32, 8, 8), 256, 0, stream>>>(y, yp);
        mgemm_k<0><<<dim3(4, 16, 8), 256, 0, stream>>>(A_lay + (size_t)l * 262144,
                                                       b_lay + l * 512, yp, o, 512, 512);
        ln_k<<<dim3(64, 8, 2), 256, 0, stream>>>(o, z, ln_gr, ln_gi, ln_br, ln_bi, l);
    }

    // ---- decoder: z -> zp, GEMM -> d_out interleaved (overwrites all scratch) ----
    tr_k<1><<<dim3(32, 8, 8), 256, 0, stream>>>(z, zp);
    mgemm_k<1><<<dim3(9, 16, 8), 256, 0, stream>>>(A_dec, b_dec, zp, (float*)d_out, 1028, 512);
}

// Round 4
// 723.188 us; speedup vs baseline: 2.4347x; 1.0004x over previous
//
#include <hip/hip_runtime.h>
#include <cstddef>
#include <cstdint>

// B=8, C=2, Hf=257, T=2048, D_IN=514, DM=256, NL=4, N=32
// Activations: fp32 planes (b, 2*DM=512, T). GEMMs run bf16 MFMA with
// k-major bf16 activation copies (b, T, Kp).

typedef __attribute__((ext_vector_type(8))) short short8;
typedef __attribute__((ext_vector_type(4))) float float4v;

__device__ __forceinline__ unsigned short f2bf(float f) {
    union { float f; unsigned u; } v; v.f = f;
    const unsigned r = v.u + 0x7fffu + ((v.u >> 16) & 1u);  // RNE
    return (unsigned short)(r >> 16);
}

__device__ __forceinline__ float gelu_tanh(float x) {
    const float x3 = x * x * x;
    const float v  = 0.7978845608028654f * (x + 0.044715f * x3);
    const float e  = __expf(2.f * v);
    const float th = 1.f - 2.f / (e + 1.f);
    return 0.5f * x * (1.f + th);
}

#define ASYNC_COPY16(gp, lp) __builtin_amdgcn_global_load_lds( \
    (const __attribute__((address_space(1))) unsigned int*)(gp), \
    (__attribute__((address_space(3))) unsigned int*)(lp), 16, 0, 0)

// ---------- builders: bf16 real-rep of complex weights, padded ----------
__global__ __launch_bounds__(256) void buildw_k(
    const float* __restrict__ Wr, const float* __restrict__ Wi,
    unsigned short* __restrict__ A, int G, int H, int Hoff, int Kp, int Mp)
{
    const long long i = (long long)blockIdx.x * 256 + threadIdx.x;
    if (i >= (long long)Mp * Kp) return;
    const int m = (int)(i / Kp), k = (int)(i % Kp);
    float val = 0.f;
    if (m < 2 * G) {
        const int ri = m >= G;
        const int g = m - ri * G;
        const int blk = k >= Hoff;
        const int hh = k - blk * Hoff;
        if (hh < H) {
            const float wr = Wr[(size_t)g * H + hh];
            const float wi = Wi[(size_t)g * H + hh];
            val = ri ? (blk ? wr : wi) : (blk ? -wi : wr);
        }
    }
    A[i] = f2bf(val);
}

__global__ __launch_bounds__(256) void build_bias_k(
    const float* __restrict__ br, const float* __restrict__ bi,
    float* __restrict__ bias, int G)
{
    const int i = blockIdx.x * 256 + threadIdx.x;
    if (i < G) bias[i] = br[i];
    else if (i < 2 * G) bias[i] = bi[i - G];
}

// ---------- encoder input pack: x (b,514,T,2) fp32 -> xp (b,T,1056) bf16 ----------
__global__ __launch_bounds__(256) void packx_k(const float* __restrict__ x,
                                               unsigned short* __restrict__ xp)
{
    const int t0 = blockIdx.x * 64, d0 = blockIdx.y * 64, b = blockIdx.z;
    __shared__ unsigned short tr_[64][72];
    __shared__ unsigned short ti_[64][72];
    const int tid = threadIdx.x;
    const int tp = tid & 31, dl0 = tid >> 5;
#pragma unroll
    for (int p = 0; p < 8; ++p) {
        const int d = dl0 + p * 8;
        const int gd = d0 + d;
        float4 v = make_float4(0.f, 0.f, 0.f, 0.f);
        if (gd < 514) v = *(const float4*)(x + (((size_t)b * 514 + gd) * 2048 + t0 + tp * 2) * 2);
        tr_[tp * 2 + 0][d] = f2bf(v.x); ti_[tp * 2 + 0][d] = f2bf(v.y);
        tr_[tp * 2 + 1][d] = f2bf(v.z); ti_[tp * 2 + 1][d] = f2bf(v.w);
    }
    __syncthreads();
    const int dc = tid & 7;
    const int kloc = d0 + dc * 8;
    if (kloc < 528) {
#pragma unroll
        for (int p = 0; p < 2; ++p) {
            const int t = (tid >> 3) + p * 32;
            const size_t rowb = ((size_t)b * 2048 + t0 + t) * 1056;
            *(short8*)&xp[rowb + kloc]       = *(const short8*)&tr_[t][dc * 8];
            *(short8*)&xp[rowb + 528 + kloc] = *(const short8*)&ti_[t][dc * 8];
        }
    }
}

// ---------- transpose planes (b,512,T) -> k-major (b,T,512) bf16 ----------
template<int SRC32>
__global__ __launch_bounds__(256) void tr_k(const void* __restrict__ src,
                                            unsigned short* __restrict__ dst)
{
    const int t0 = blockIdx.x * 64, k0 = blockIdx.y * 64, b = blockIdx.z;
    __shared__ unsigned short tile[64][72];
    const int tid = threadIdx.x;
    if (SRC32) {
        const float* sf = (const float*)src;
        const int tp = tid & 31, kl0 = tid >> 5;
#pragma unroll
        for (int p = 0; p < 8; ++p) {
            const int kl = kl0 + p * 8;
            const float2 v = *(const float2*)(sf + ((size_t)b * 512 + k0 + kl) * 2048 + t0 + tp * 2);
            tile[tp * 2 + 0][kl] = f2bf(v.x);
            tile[tp * 2 + 1][kl] = f2bf(v.y);
        }
    } else {
        const unsigned short* su = (const unsigned short*)src;
        const int toct = tid & 7, kl0 = tid >> 3;
#pragma unroll
        for (int p = 0; p < 2; ++p) {
            const int kl = kl0 + p * 32;
            const short8 v = *(const short8*)(su + ((size_t)b * 512 + k0 + kl) * 2048 + t0 + toct * 8);
#pragma unroll
            for (int j = 0; j < 8; ++j) tile[toct * 8 + j][kl] = ((const unsigned short*)&v)[j];
        }
    }
    __syncthreads();
    const int dc = tid & 7;
#pragma unroll
    for (int p = 0; p < 2; ++p) {
        const int t = (tid >> 3) + p * 32;
        *(short8*)&dst[((size_t)b * 2048 + t0 + t) * 512 + k0 + dc * 8] = *(const short8*)&tile[t][dc * 8];
    }
}

// ---------- bf16 MFMA GEMM: out(b,M,T) = A(Mp x Kp) * Bm(b,T,Kp)^T + bias ----------
template<int MODE>
__global__ __launch_bounds__(256, 2) void mgemm_k(
    const unsigned short* __restrict__ A, const float* __restrict__ bias,
    const unsigned short* __restrict__ Bm, float* __restrict__ out,
    int M, int Kp)
{
    __shared__ unsigned short As[4096];  // [m 0..127][k 0..31]
    __shared__ unsigned short Bs[4096];  // [t 0..127][k 0..31]
    const int tid = threadIdx.x;
    const int w = tid >> 6, lane = tid & 63;
    const int m0 = blockIdx.x * 128, t0 = blockIdx.y * 128, b = blockIdx.z;
    const int wm = w & 1, wn = w >> 1;

    const unsigned short* Ab = A + (size_t)m0 * Kp;
    const unsigned short* Bb = Bm + ((size_t)b * 2048 + t0) * Kp;

    const int c0 = w * 64 + lane;
    const int r0 = c0 >> 2, q0 = (c0 & 3) * 8;
    const int c1 = c0 + 256;
    const int r1 = c1 >> 2, q1 = (c1 & 3) * 8;
    unsigned short* As0 = &As[(size_t)(w * 64) * 8];
    unsigned short* As1 = &As[(size_t)(w * 64 + 256) * 8];
    unsigned short* Bs0 = &Bs[(size_t)(w * 64) * 8];
    unsigned short* Bs1 = &Bs[(size_t)(w * 64 + 256) * 8];

    float4v acc[4][4];
#pragma unroll
    for (int i = 0; i < 4; ++i)
#pragma unroll
        for (int j = 0; j < 4; ++j) acc[i][j] = (float4v){0.f, 0.f, 0.f, 0.f};

    const int arow = wm * 64 + (lane & 15);
    const int brow = wn * 64 + (lane & 15);
    const int kq = (lane >> 4) * 8;

    for (int k0 = 0; k0 < Kp; k0 += 32) {
        ASYNC_COPY16(Ab + (size_t)r0 * Kp + k0 + q0, As0);
        ASYNC_COPY16(Ab + (size_t)r1 * Kp + k0 + q1, As1);
        ASYNC_COPY16(Bb + (size_t)r0 * Kp + k0 + q0, Bs0);
        ASYNC_COPY16(Bb + (size_t)r1 * Kp + k0 + q1, Bs1);
        __syncthreads();
        short8 af[4], bf[4];
#pragma unroll
        for (int i = 0; i < 4; ++i) af[i] = *(const short8*)&As[(arow + i * 16) * 32 + kq];
#pragma unroll
        for (int j = 0; j < 4; ++j) bf[j] = *(const short8*)&Bs[(brow + j * 16) * 32 + kq];
#pragma unroll
        for (int i = 0; i < 4; ++i)
#pragma unroll
            for (int j = 0; j < 4; ++j)
                acc[i][j] = __builtin_amdgcn_mfma_f32_16x16x32_bf16(af[i], bf[j], acc[i][j], 0, 0, 0);
        __syncthreads();
    }

    const int col = lane & 15;
    const int rq = (lane >> 4) * 4;
#pragma unroll
    for (int i = 0; i < 4; ++i) {
        const int mloc = wm * 64 + i * 16 + rq;
#pragma unroll
        for (int r = 0; r < 4; ++r) {
            const int m = m0 + mloc + r;
            if (MODE == 1 && m >= M) continue;
            const float bs = bias[m];
#pragma unroll
            for (int j = 0; j < 4; ++j) {
                const int t = t0 + wn * 64 + j * 16 + col;
                const float vv = acc[i][j][r] + bs;
                if (MODE == 0) {
                    out[((size_t)b * 512 + m) * 2048 + t] = vv;
                } else {
                    const int comp = m >= 514;
                    const int g = m - 514 * comp;
                    out[(((size_t)b * 514 + g) * 2048 + t) * 2 + comp] = vv;
                }
            }
        }
    }
}

// ---------- S4D diagonal SSM scan + D-skip + gelu -> bf16 planes ----------
// Block = 256 threads (4 waves) per (b,h). Wave wv owns modes 8wv..8wv+7;
// lane c owns timesteps [c*32, c*32+32). Partials combined in LDS.
// __launch_bounds__(256,3): VGPR cap ~170 so ur/ui/yr/yi (128 regs) stay in
// arch VGPRs — at the default cap (80) the compiler spills them to AGPRs and
// ~2.8x-inflates the VALU stream with v_accvgpr moves (R3 post-mortem).
__global__ __launch_bounds__(256, 3) void s4scan_k(
    const float* __restrict__ z, unsigned short* __restrict__ y,
    const float* __restrict__ log_dt, const float* __restrict__ log_A_real,
    const float* __restrict__ A_imag, const float* __restrict__ C_r,
    const float* __restrict__ C_i, const float* __restrict__ Dsk, int l)
{
    const int h = blockIdx.x, b = blockIdx.y;
    const int tid = threadIdx.x;
    const int wv = tid >> 6, lane = tid & 63;
    __shared__ float2 wsh[32], csh[32];
    __shared__ float dsh;
    __shared__ float buf[2][64][34];

    if (tid < 32) {
        const size_t pidx = ((size_t)l * 256 + h) * 32 + tid;
        const float dt = __expf(log_dt[l * 256 + h]);
        const float Ar = -__expf(log_A_real[pidx]);
        const float Ai = A_imag[pidx];
        const float er = __expf(Ar * dt);
        float sv, cv;
        __sincosf(Ai * dt, &sv, &cv);
        const float wr = er * cv, wi = er * sv;
        const float den = 1.f / (Ar * Ar + Ai * Ai);
        const float nr = wr - 1.f, ni = wi;
        const float qr = (nr * Ar + ni * Ai) * den;
        const float qi = (ni * Ar - nr * Ai) * den;
        const float cr = C_r[pidx], ci = C_i[pidx];
        wsh[tid] = make_float2(wr, wi);
        csh[tid] = make_float2(cr * qr - ci * qi, cr * qi + ci * qr);
    }
    if (tid == 32) dsh = Dsk[l * 256 + h];
    __syncthreads();

    const float* zrp = z + ((size_t)b * 512 + h) * 2048 + lane * 32;
    const float* zip = zrp + 256 * 2048;
    float ur[32], ui[32], yr[32], yi[32];
#pragma unroll
    for (int j = 0; j < 8; ++j) {
        *(float4*)&ur[j * 4] = *(const float4*)(zrp + j * 4);
        *(float4*)&ui[j * 4] = *(const float4*)(zip + j * 4);
    }
#pragma unroll
    for (int t = 0; t < 32; ++t) { yr[t] = 0.f; yi[t] = 0.f; }

    for (int nn = 0; nn < 8; ++nn) {
        const float2 wm = wsh[wv * 8 + nn], ct = csh[wv * 8 + nn];
        // pass 1: chunk-local final state (zero init)
        float xr = 0.f, xi = 0.f;
#pragma unroll
        for (int t = 0; t < 32; ++t) {
            const float nxr = __builtin_fmaf(wm.x, xr, __builtin_fmaf(-wm.y, xi, ur[t]));
            const float nxi = __builtin_fmaf(wm.x, xi, __builtin_fmaf(wm.y, xr, ui[t]));
            xr = nxr; xi = nxi;
        }
        // f = w^32
        float fr = wm.x, fi = wm.y;
#pragma unroll
        for (int s = 0; s < 5; ++s) { const float a2 = fr * fr - fi * fi, b2 = 2.f * fr * fi; fr = a2; fi = b2; }
        // inclusive wave prefix over chunk-final states with multiplier f
        float qrv = xr, qiv = xi, pr = fr, pi = fi;
#pragma unroll
        for (int s = 0; s < 6; ++s) {
            const int d = 1 << s;
            const float sr = __shfl_up(qrv, (unsigned)d);
            const float si = __shfl_up(qiv, (unsigned)d);
            if (lane >= d) {
                qrv += pr * sr - pi * si;
                qiv += pr * si + pi * sr;
            }
            const float a2 = pr * pr - pi * pi, b2 = 2.f * pr * pi;
            pr = a2; pi = b2;
        }
        float vr = __shfl_up(qrv, 1u);
        float vi = __shfl_up(qiv, 1u);
        if (lane == 0) { vr = 0.f; vi = 0.f; }
        // pass 2: carry-init scan + output accumulation
        float sr2 = vr, si2 = vi;
#pragma unroll
        for (int t = 0; t < 32; ++t) {
            const float nsr = __builtin_fmaf(wm.x, sr2, __builtin_fmaf(-wm.y, si2, ur[t]));
            const float nsi = __builtin_fmaf(wm.x, si2, __builtin_fmaf(wm.y, sr2, ui[t]));
            sr2 = nsr; si2 = nsi;
            yr[t] += ct.x * sr2 - ct.y * si2;
            yi[t] += ct.x * si2 + ct.y * sr2;
        }
    }

    // fold D-skip into wave 0's partial (linear term)
    if (wv == 0) {
        const float dv = dsh;
#pragma unroll
        for (int t = 0; t < 32; ++t) {
            yr[t] = __builtin_fmaf(dv, ur[t], yr[t]);
            yi[t] = __builtin_fmaf(dv, ui[t], yi[t]);
        }
    }

    // 4-phase LDS reduction (float2 ops; stride 34 -> 2-way bank aliasing, free)
#pragma unroll
    for (int ph = 0; ph < 4; ++ph) {
        if (wv == ph) {
            if (ph == 0) {
#pragma unroll
                for (int j = 0; j < 16; ++j) {
                    *(float2*)&buf[0][lane][j * 2] = make_float2(yr[j * 2], yr[j * 2 + 1]);
                    *(float2*)&buf[1][lane][j * 2] = make_float2(yi[j * 2], yi[j * 2 + 1]);
                }
            } else {
#pragma unroll
                for (int j = 0; j < 16; ++j) {
                    float2 a = *(const float2*)&buf[0][lane][j * 2];
                    a.x += yr[j * 2]; a.y += yr[j * 2 + 1];
                    *(float2*)&buf[0][lane][j * 2] = a;
                    float2 bq = *(const float2*)&buf[1][lane][j * 2];
                    bq.x += yi[j * 2]; bq.y += yi[j * 2 + 1];
                    *(float2*)&buf[1][lane][j * 2] = bq;
                }
            }
        }
        __syncthreads();
    }

    // final: gelu + bf16 pack + coalesced stores. Thread tid owns t = tid*8..+8.
    const int chunk = tid >> 2, pos = (tid & 3) * 8;
    unsigned short* yrp = y + ((size_t)b * 512 + h) * 2048 + tid * 8;
    unsigned short* yip = yrp + 256 * 2048;
    {
        short8 vr8, vi8;
#pragma unroll
        for (int j = 0; j < 8; ++j) {
            ((unsigned short*)&vr8)[j] = f2bf(gelu_tanh(buf[0][chunk][pos + j]));
            ((unsigned short*)&vi8)[j] = f2bf(gelu_tanh(buf[1][chunk][pos + j]));
        }
        *(short8*)yrp = vr8;
        *(short8*)yip = vi8;
    }
}

// ---------- residual + channel LayerNorm (fp32 planes) ----------
__global__ __launch_bounds__(256) void ln_k(
    const float* __restrict__ o, float* __restrict__ z,
    const float* __restrict__ gamr, const float* __restrict__ gami,
    const float* __restrict__ betr, const float* __restrict__ beti, int l)
{
    const int tt = blockIdx.x, b = blockIdx.y, comp = blockIdx.z;
    const int tid = threadIdx.x;
    const int tloc = tid & 31, gq = tid >> 5;
    __shared__ float tile[256][33];
    __shared__ float red[2][8][32];
    __shared__ float stat[2][32];
    const int t0 = tt * 32;
    const size_t base = ((size_t)b * 512 + comp * 256) * 2048 + t0 + tloc;

#pragma unroll 4
    for (int j = 0; j < 32; ++j) {
        const int g = j * 8 + gq;
        const size_t idx = base + (size_t)g * 2048;
        tile[g][tloc] = o[idx] + z[idx];
    }
    __syncthreads();
    float s = 0.f, sq = 0.f;
#pragma unroll 4
    for (int g2 = 0; g2 < 32; ++g2) {
        const float v = tile[gq * 32 + g2][tloc];
        s += v; sq += v * v;
    }
    red[0][gq][tloc] = s; red[1][gq][tloc] = sq;
    __syncthreads();
    if (tid < 32) {
        float S = 0.f, SQ = 0.f;
#pragma unroll
        for (int q = 0; q < 8; ++q) { S += red[0][q][tid]; SQ += red[1][q][tid]; }
        const float m = S * (1.f / 256.f);
        const float var = SQ * (1.f / 256.f) - m * m;
        stat[0][tid] = m;
        stat[1][tid] = rsqrtf(var + 1e-5f);
    }
    __syncthreads();
    const float* gam = (comp ? gami : gamr) + l * 256;
    const float* bet = (comp ? beti : betr) + l * 256;
    const float m = stat[0][tloc], rs = stat[1][tloc];
#pragma unroll 4
    for (int j = 0; j < 32; ++j) {
        const int g = j * 8 + gq;
        z[base + (size_t)g * 2048] = (tile[g][tloc] - m) * rs * gam[g] + bet[g];
    }
}

extern "C" void kernel_launch(void* const* d_in, const int* in_sizes, int n_in,
                              void* d_out, int out_size, void* d_ws, size_t ws_size,
                              hipStream_t stream)
{
    const float* x        = (const float*)d_in[0];
    const float* enc_Wr   = (const float*)d_in[1];
    const float* enc_Wi   = (const float*)d_in[2];
    const float* enc_br   = (const float*)d_in[3];
    const float* enc_bi   = (const float*)d_in[4];
    const float* log_dt   = (const float*)d_in[5];
    const float* log_A_r  = (const float*)d_in[6];
    const float* A_imag   = (const float*)d_in[7];
    const float* C_r      = (const float*)d_in[8];
    const float* C_i      = (const float*)d_in[9];
    const float* Dp       = (const float*)d_in[10];
    const float* out_Wr   = (const float*)d_in[11];
    const float* out_Wi   = (const float*)d_in[12];
    const float* out_br   = (const float*)d_in[13];
    const float* out_bi   = (const float*)d_in[14];
    const float* ln_gr    = (const float*)d_in[15];
    const float* ln_gi    = (const float*)d_in[16];
    const float* ln_br    = (const float*)d_in[17];
    const float* ln_bi    = (const float*)d_in[18];
    const float* dec_Wr   = (const float*)d_in[19];
    const float* dec_Wi   = (const float*)d_in[20];
    const float* dec_br   = (const float*)d_in[21];
    const float* dec_bi   = (const float*)d_in[22];

    // ---- workspace layout (bytes) ----
    uint8_t* W = (uint8_t*)d_ws;
    float* z             = (float*)W;                       // 33,554,432
    unsigned short* zp   = (unsigned short*)(W + 33554432); // 16,777,216
    unsigned short* A_enc= (unsigned short*)(W + 50331648); // 512x1056x2  = 1,081,344
    unsigned short* A_lay= (unsigned short*)(W + 51412992); // 4x512x512x2 = 2,097,152
    unsigned short* A_dec= (unsigned short*)(W + 53510144); // 1152x512x2  = 1,179,648
    float* b_enc         = (float*)(W + 54689792);          // 512 f
    float* b_lay         = (float*)(W + 54691840);          // 2048 f
    float* b_dec         = (float*)(W + 54700032);          // 1028 f

    // ---- d_out doubles as scratch (67.37 MB total) ----
    float* o            = (float*)d_out;                                   // 33,554,432
    unsigned short* y   = (unsigned short*)((uint8_t*)d_out + 33554432);   // 16,777,216
    unsigned short* yp  = (unsigned short*)((uint8_t*)d_out + 50331648);   // 16,777,216
    unsigned short* xp  = (unsigned short*)d_out;  // 34,603,008; dead after encoder GEMM

    // ---- build weights/biases ----
    buildw_k<<<2112, 256, 0, stream>>>(enc_Wr, enc_Wi, A_enc, 256, 514, 528, 1056, 512);
    for (int l = 0; l < 4; ++l)
        buildw_k<<<1024, 256, 0, stream>>>(out_Wr + (size_t)l * 65536, out_Wi + (size_t)l * 65536,
                                           A_lay + (size_t)l * 262144, 256, 256, 256, 512, 512);
    buildw_k<<<2304, 256, 0, stream>>>(dec_Wr, dec_Wi, A_dec, 514, 256, 256, 512, 1152);
    build_bias_k<<<2, 256, 0, stream>>>(enc_br, enc_bi, b_enc, 256);
    for (int l = 0; l < 4; ++l)
        build_bias_k<<<2, 256, 0, stream>>>(out_br + l * 256, out_bi + l * 256, b_lay + l * 512, 256);
    build_bias_k<<<5, 256, 0, stream>>>(dec_br, dec_bi, b_dec, 514);

    // ---- encoder: pack x -> xp, GEMM -> z ----
    packx_k<<<dim3(32, 9, 8), 256, 0, stream>>>(x, xp);
    mgemm_k<0><<<dim3(4, 16, 8), 256, 0, stream>>>(A_enc, b_enc, xp, z, 512, 1056);

    // ---- layers ----
    for (int l = 0; l < 4; ++l) {
        s4scan_k<<<dim3(256, 8), 256, 0, stream>>>(z, y, log_dt, log_A_r, A_imag, C_r, C_i, Dp, l);
        tr_k<0><<<dim3(32, 8, 8), 256, 0, stream>>>(y, yp);
        mgemm_k<0><<<dim3(4, 16, 8), 256, 0, stream>>>(A_lay + (size_t)l * 262144,
                                                       b_lay + l * 512, yp, o, 512, 512);
        ln_k<<<dim3(64, 8, 2), 256, 0, stream>>>(o, z, ln_gr, ln_gi, ln_br, ln_bi, l);
    }

    // ---- decoder: z -> zp, GEMM -> d_out interleaved (overwrites all scratch) ----
    tr_k<1><<<dim3(32, 8, 8), 256, 0, stream>>>(z, zp);
    mgemm_k<1><<<dim3(9, 16, 8), 256, 0, stream>>>(A_dec, b_dec, zp, (float*)d_out, 1028, 512);
}